// Round 17
// baseline (242.933 us; speedup 1.0000x reference)
//
#include <hip/hip_runtime.h>
#include <hip/hip_bf16.h>
#include <math.h>
#include <float.h>

#define NROWS  10000
#define INDIM  512
#define KSPLIT 384     // OpenBLAS sgemm kc split (Round-3 passing arithmetic — do not touch)
#define HID    128
#define NSTRIP 16
#define STRIPW 625
#define CHUNK  64
#define NCHUNK 10      // 10*64 = 640 >= 625
#define CAPS   64      // per-(row,strip) capacity: lambda~30.5 -> P(ovf)~8e-7/seg
#define RESC   32      // exactly-rescored per row
#define KOUT   14
#define ZPADR  10240   // zb pad rows (max A row 10239, max staged B row 10014)
#define GRIDX  40      // ceil(10000/256)
#define NBLK   640     // GRIDX * NSTRIP
#define Z4TOT  25000000
#define Z4BLK  39063   // ceil(25e6 / 640)
#define Z4CHK  3907    // ceil(Z4BLK / NCHUNK)
#define C_TAU  2.05f

using short8 = __attribute__((ext_vector_type(8))) short;
using f32x4  = __attribute__((ext_vector_type(4))) float;

// ---------------------------------------------------------------------------
// K1: bit-replicates numpy f32 (Round-3 passing arithmetic). feat rows staged
// once into LDS then broadcast-read (R15-proven: 15us faster than direct
// global — L1 thrash on the serial FMA chain). FMA order unchanged.
// grid = 1280 x 128 (blocks 1250+ zero zb pad rows).
// ---------------------------------------------------------------------------
__global__ __launch_bounds__(128)
void k_projnorm(const float* __restrict__ feat, const float* __restrict__ W,
                const float* __restrict__ b, float* __restrict__ z32,
                __hip_bfloat16* __restrict__ zb) {
    const int h = threadIdx.x;
    const int row0 = blockIdx.x * 8;
    if (row0 >= NROWS) {                 // zero bf16 pad rows
#pragma unroll
        for (int r = 0; r < 8; ++r)
            if (row0 + r < ZPADR) zb[(size_t)(row0 + r) * HID + h] = __float2bfloat16(0.f);
        return;
    }
    __shared__ float fl[8][INDIM];       // 16 KB staged feat rows
#pragma unroll
    for (int i = 0; i < 8; ++i)
        *(float4*)&fl[i][h * 4] = *(const float4*)(feat + (size_t)(row0 + i) * INDIM + h * 4);
    __syncthreads();

    float accA[8], accB[8];
#pragma unroll
    for (int r = 0; r < 8; ++r) { accA[r] = 0.f; accB[r] = 0.f; }
#pragma unroll 4
    for (int k4 = 0; k4 < 96; ++k4) {    // k = 0..383 (chain A)
        const int k = k4 * 4;
        const float w0 = W[(k + 0) * HID + h];
        const float w1 = W[(k + 1) * HID + h];
        const float w2 = W[(k + 2) * HID + h];
        const float w3 = W[(k + 3) * HID + h];
#pragma unroll
        for (int r = 0; r < 8; ++r) {
            const float4 f = *(const float4*)&fl[r][k];
            accA[r] = fmaf(f.x, w0, accA[r]);
            accA[r] = fmaf(f.y, w1, accA[r]);
            accA[r] = fmaf(f.z, w2, accA[r]);
            accA[r] = fmaf(f.w, w3, accA[r]);
        }
    }
#pragma unroll 4
    for (int k4 = 96; k4 < 128; ++k4) {  // k = 384..511 (chain B)
        const int k = k4 * 4;
        const float w0 = W[(k + 0) * HID + h];
        const float w1 = W[(k + 1) * HID + h];
        const float w2 = W[(k + 2) * HID + h];
        const float w3 = W[(k + 3) * HID + h];
#pragma unroll
        for (int r = 0; r < 8; ++r) {
            const float4 f = *(const float4*)&fl[r][k];
            accB[r] = fmaf(f.x, w0, accB[r]);
            accB[r] = fmaf(f.y, w1, accB[r]);
            accB[r] = fmaf(f.z, w2, accB[r]);
            accB[r] = fmaf(f.w, w3, accB[r]);
        }
    }
    __shared__ float zl[8][HID];
    __shared__ float nrm[8];
    const float bh = b[h];
#pragma unroll
    for (int r = 0; r < 8; ++r)
        zl[r][h] = __fadd_rn(__fadd_rn(accA[r], accB[r]), bh);
    __syncthreads();
    if (h < 8) {
        float rr[8];
#pragma unroll
        for (int j = 0; j < 8; ++j) rr[j] = __fmul_rn(zl[h][j], zl[h][j]);
        for (int i = 8; i < HID; i += 8)
#pragma unroll
            for (int j = 0; j < 8; ++j)
                rr[j] = __fadd_rn(rr[j], __fmul_rn(zl[h][i + j], zl[h][i + j]));
        const float s = __fadd_rn(
            __fadd_rn(__fadd_rn(rr[0], rr[1]), __fadd_rn(rr[2], rr[3])),
            __fadd_rn(__fadd_rn(rr[4], rr[5]), __fadd_rn(rr[6], rr[7])));
        nrm[h] = fmaxf(__fsqrt_rn(s), 1e-12f);
    }
    __syncthreads();
#pragma unroll
    for (int r = 0; r < 8; ++r) {
        const float v = __fdiv_rn(zl[r][h], nrm[r]);
        z32[(size_t)(row0 + r) * HID + h] = v;
        zb [(size_t)(row0 + r) * HID + h] = __float2bfloat16(v);
    }
}

// ---------------------------------------------------------------------------
// K2: 2-output-tile 8-wave MFMA candidate generator: 256 rows/block, each
// B-fragment ds_read feeds TWO mfmas (halves LDS reads + barriers vs R15).
// Double-buffered swizzled LDS, adaptive tau, LDS-counter append, fused NT
// output zeroing. grid = (40, 16), block 512.
// ---------------------------------------------------------------------------
__global__ __launch_bounds__(512)
void k_cand(const __hip_bfloat16* __restrict__ zbp, f32x4* __restrict__ out4,
            int* __restrict__ cnt4, unsigned int* __restrict__ list) {
    __shared__ ushort Bt[2][8192];      // 2 x 16 KB, swizzled [64 j][128 k] bf16
    __shared__ int lcnt[256];           // per-row append counters
    const char* zbb = (const char*)zbp;
    const int tid = threadIdx.x, lane = tid & 63, wid = tid >> 6;
    const int row0 = blockIdx.x * 256;
    const int strip = blockIdx.y;
    const int jbase = strip * STRIPW;
    const int bid = strip * GRIDX + blockIdx.x;
    const int row_g0 = row0 + wid * 16 + (lane & 15);   // tile 0: rows 0..127
    const int row_g1 = row_g0 + 128;                    // tile 1: rows 128..255
    const int rloc0 = wid * 16 + (lane & 15);
    const int rloc1 = rloc0 + 128;
    const int swz = (lane & 7) << 4;
    const size_t seg0 = ((size_t)row_g0 * NSTRIP + strip) * CAPS;
    const size_t seg1 = ((size_t)row_g1 * NSTRIP + strip) * CAPS;
    const bool rowok1 = row_g1 < NROWS;                 // tile-1 pad guard

    if (tid < 256) lcnt[tid] = 0;

    // A fragments for both tiles (mfma B-operand position)
    short8 afr0[4], afr1[4];
    {
        const char* a0 = zbb + (size_t)row_g0 * 256 + ((lane >> 4) * 16);
        const char* a1 = zbb + (size_t)row_g1 * 256 + ((lane >> 4) * 16);
#pragma unroll
        for (int ks = 0; ks < 4; ++ks) {
            afr0[ks] = *(const short8*)(a0 + ks * 64);
            afr1[ks] = *(const short8*)(a1 + ks * 64);
        }
    }

    // staging map: thread stages 32 B of the 16 KB chunk
    const int sjl = tid >> 3;           // local j row 0..63
    const int sir = (tid & 7) * 32;     // in-row byte 0..224
    const int sw0 = sir ^ ((sjl & 7) << 4);
    const int sw1 = (sir + 16) ^ ((sjl & 7) << 4);

    // prologue: stage chunk 0 -> buf 0
    {
        const char* src = zbb + (size_t)(jbase + sjl) * 256 + sir;
        const uint4 d0 = *(const uint4*)(src);
        const uint4 d1 = *(const uint4*)(src + 16);
        char* dst = (char*)Bt[0] + (size_t)sjl * 256;
        *(uint4*)(dst + sw0) = d0;
        *(uint4*)(dst + sw1) = d1;
    }
    __syncthreads();

    const size_t zb0 = (size_t)bid * Z4BLK;
    int zlen = Z4TOT - (int)zb0; if (zlen > Z4BLK) zlen = Z4BLK;
    f32x4* zp = out4 + zb0;
    const f32x4 zero4 = {0.f, 0.f, 0.f, 0.f};

    float ss0 = 0.f, ss1 = 0.f;   // per-tile row-pooled sum of squared sims

#pragma unroll 1
    for (int c = 0; c < NCHUNK; ++c) {
        const int jc = c * CHUNK;
        const char* cur = (const char*)Bt[c & 1];

        // issue next-chunk global loads early
        uint4 st0, st1;
        const bool nx = (c + 1 < NCHUNK);
        if (nx) {
            const char* src = zbb + (size_t)(jbase + jc + CHUNK + sjl) * 256 + sir;
            st0 = *(const uint4*)(src);
            st1 = *(const uint4*)(src + 16);
        }

        // fused output zeroing slice (NT streaming; drains under compute)
        {
            const int z0 = c * Z4CHK;
            int ze = z0 + Z4CHK; if (ze > zlen) ze = zlen;
            for (int i = z0 + tid; i < ze; i += 512)
                __builtin_nontemporal_store(zero4, zp + i);
        }

        // adaptive thresholds (same formula per tile; stats identical to R15)
        float tau0, tau1;
        if (c == 0) { tau0 = 0.10f; tau1 = 0.10f; }
        else {
            const float n = 64.f * (float)c;
            const float w = 1.f - 3.f * __frsqrt_rn(2.f * n);
            tau0 = fmaxf(C_TAU * w * __fsqrt_rn(ss0 / n), 0.08f);
            tau1 = fmaxf(C_TAU * w * __fsqrt_rn(ss1 / n), 0.08f);
        }

        // 16 ds_read_b128, 32 mfma: each bfr feeds BOTH tiles
        f32x4 acc0[4], acc1[4];
#pragma unroll
        for (int t = 0; t < 4; ++t) {
            acc0[t] = (f32x4){0.f, 0.f, 0.f, 0.f};
            acc1[t] = (f32x4){0.f, 0.f, 0.f, 0.f};
            const char* rp = cur + (size_t)(t * 16 + (lane & 15)) * 256;
#pragma unroll
            for (int ks = 0; ks < 4; ++ks) {
                const short8 bfr = *(const short8*)(rp + ((ks * 64 + (lane >> 4) * 16) ^ swz));
                acc0[t] = __builtin_amdgcn_mfma_f32_16x16x32_bf16(bfr, afr0[ks], acc0[t], 0, 0, 0);
                acc1[t] = __builtin_amdgcn_mfma_f32_16x16x32_bf16(bfr, afr1[ks], acc1[t], 0, 0, 0);
            }
        }

        // sigma accumulation + LDS-counter append (fire-and-forget stores)
        float ssl0 = 0.f, ssl1 = 0.f;
#pragma unroll
        for (int t = 0; t < 4; ++t) {
#pragma unroll
            for (int r = 0; r < 4; ++r) {
                const int js = jc + t * 16 + ((lane >> 4) << 2) + r;
                const int jg = jbase + js;
                const bool okj = (js < STRIPW);
                const float v0 = acc0[t][r], v1 = acc1[t][r];
                const bool ok0 = okj && (jg != row_g0);
                const bool ok1 = okj && (jg != row_g1) && rowok1;
                ssl0 += ok0 ? v0 * v0 : 0.f;
                ssl1 += ok1 ? v1 * v1 : 0.f;
                if (ok0 && v0 > tau0) {
                    const unsigned int u = __builtin_bit_cast(unsigned int, v0);
                    const unsigned int pk = (((u + 0x8000u) >> 16) << 16) | (unsigned int)jg;
                    const int pos = atomicAdd(&lcnt[rloc0], 1);
                    if (pos < CAPS) list[seg0 + pos] = pk;
                }
                if (ok1 && v1 > tau1) {
                    const unsigned int u = __builtin_bit_cast(unsigned int, v1);
                    const unsigned int pk = (((u + 0x8000u) >> 16) << 16) | (unsigned int)jg;
                    const int pos = atomicAdd(&lcnt[rloc1], 1);
                    if (pos < CAPS) list[seg1 + pos] = pk;
                }
            }
        }
        ssl0 += __shfl_xor(ssl0, 16, 64);   // pool over the row's 4 lanes
        ssl0 += __shfl_xor(ssl0, 32, 64);
        ssl1 += __shfl_xor(ssl1, 16, 64);
        ssl1 += __shfl_xor(ssl1, 32, 64);
        ss0 += ssl0;
        ss1 += ssl1;

        // write staged regs -> other buffer
        if (nx) {
            char* wb = (char*)Bt[(c + 1) & 1] + (size_t)sjl * 256;
            *(uint4*)(wb + sw0) = st0;
            *(uint4*)(wb + sw1) = st1;
        }
        __syncthreads();
    }

    // flush per-(row, strip) counts (this block is the exclusive owner)
    if (tid < 256) {
        const int row = row0 + tid;
        if (row < NROWS) cnt4[row * NSTRIP + strip] = lcnt[tid];
    }
}

// ---------------------------------------------------------------------------
// K3: approx-top-32 of the 16 per-strip segments (packed bf16|idx keys,
// 16 regs/lane = 1024 slots exactly), exact rescore of those 32 with the
// bit-exact sequential f32 FMA chain, exact top-14 by (value desc, idx asc),
// scatter. Rows pre-zeroed by K2. grid = 2500 (4 rows/block, 1 wave/row).
// [R15-proven, unchanged]
// ---------------------------------------------------------------------------
#define CEK(a, b) { const unsigned int x_ = k[a], y_ = k[b]; \
    k[a] = x_ > y_ ? x_ : y_; k[b] = x_ > y_ ? y_ : x_; }

__global__ __launch_bounds__(256)
void k_select(const float* __restrict__ z32, const int* __restrict__ cnt4,
              const unsigned int* __restrict__ list, float* __restrict__ out) {
    __shared__ float zr[4][HID];
    const int tid = threadIdx.x, wid = tid >> 6, lane = tid & 63;
    const int row = blockIdx.x * 4 + wid;

    *(float2*)&zr[wid][lane * 2] = *(const float2*)(z32 + (size_t)row * HID + lane * 2);
    __syncthreads();

    unsigned int k[16];
#pragma unroll
    for (int t = 0; t < 16; ++t) {
        const int p = t * 64 + lane;          // 0..1023
        const int seg = p >> 6;               // p / CAPS (CAPS = 64)
        const int off = p & 63;
        int cn = cnt4[row * NSTRIP + seg]; if (cn > CAPS) cn = CAPS;
        k[t] = (off < cn) ? list[((size_t)row * NSTRIP + seg) * CAPS + off] : 0u;
    }

    // bitonic sort-16 descending (static indices, sentinel 0)
#pragma unroll
    for (int size = 2; size <= 16; size <<= 1) {
#pragma unroll
        for (int stride = size >> 1; stride > 0; stride >>= 1) {
#pragma unroll
            for (int i = 0; i < 16; ++i) {
                const int j = i ^ stride;
                if (j > i) {
                    if ((i & size) == 0) { CEK(i, j); } else { CEK(j, i); }
                }
            }
        }
    }

    // 32 pops by packed key (keys unique: idx in low bits); lane t keeps pop t
    unsigned int win = 0u;
#pragma unroll 1
    for (int t = 0; t < RESC; ++t) {
        unsigned int m = k[0];
#pragma unroll
        for (int msk = 1; msk <= 32; msk <<= 1) {
            const unsigned int o = (unsigned int)__shfl_xor((int)m, msk, 64);
            m = o > m ? o : m;
        }
        if (lane == t) win = m;
        if (k[0] == m && m != 0u) {
#pragma unroll
            for (int s = 0; s < 15; ++s) k[s] = k[s + 1];
            k[15] = 0u;
        }
    }

    // exact rescore (bit-exact Round-3 chain) of the 32 winners
    float ex = -INFINITY; int idx = 0x7fffffff;
    const bool act = (lane < RESC) && (win != 0u);
    if (act) {
        idx = (int)(win & 0xFFFFu);
        const float* p = z32 + (size_t)idx * HID;
        float a = 0.f;
#pragma unroll
        for (int k4 = 0; k4 < 32; ++k4) {   // strict k-ascending chain
            const float4 bb = *(const float4*)(p + k4 * 4);
            const float4 zz = *(const float4*)&zr[wid][k4 * 4];
            a = fmaf(zz.x, bb.x, a);
            a = fmaf(zz.y, bb.y, a);
            a = fmaf(zz.z, bb.z, a);
            a = fmaf(zz.w, bb.w, a);
        }
        ex = a;
    }

    bool alive = act;
#pragma unroll 1
    for (int t = 0; t < KOUT; ++t) {
        float mv = alive ? ex : -INFINITY;
        int   mi = alive ? idx : 0x7fffffff;
#pragma unroll
        for (int msk = 1; msk <= 32; msk <<= 1) {
            const float ov = __shfl_xor(mv, msk, 64);
            const int   oj = __shfl_xor(mi, msk, 64);
            const bool take = (ov > mv) || (ov == mv && oj < mi);
            mv = take ? ov : mv; mi = take ? oj : mi;
        }
        if (alive && idx == mi) {
            out[(size_t)row * NROWS + mi] = ex;
            alive = false;
        }
    }
}

// ---------------------------------------------------------------------------
extern "C" void kernel_launch(void* const* d_in, const int* in_sizes, int n_in,
                              void* d_out, int out_size, void* d_ws, size_t ws_size,
                              hipStream_t stream) {
    const float* feat = (const float*)d_in[0];
    const float* W    = (const float*)d_in[1];
    const float* b    = (const float*)d_in[2];
    float* out = (float*)d_out;

    char* ws = (char*)d_ws;
    float*          z32  = (float*)ws;                          //  5,120,000 B
    __hip_bfloat16* zb   = (__hip_bfloat16*)(ws + 5120000);     //  2,621,440 B (10240x256)
    int*            cnt4 = (int*)(ws + 7741440);                //    640,000 B (10000x16)
    unsigned int*   lst  = (unsigned int*)(ws + 8381440);       // 40,960,000 B (10000x16x64x4)

    hipLaunchKernelGGL(k_projnorm, dim3(1280),          dim3(128), 0, stream, feat, W, b, z32, zb);
    hipLaunchKernelGGL(k_cand,     dim3(GRIDX, NSTRIP), dim3(512), 0, stream, zb, (f32x4*)out, cnt4, lst);
    hipLaunchKernelGGL(k_select,   dim3(2500),          dim3(256), 0, stream, z32, cnt4, lst, out);
}

// Round 18
// 206.936 us; speedup vs baseline: 1.1740x; 1.1740x over previous
//
#include <hip/hip_runtime.h>
#include <hip/hip_bf16.h>
#include <math.h>
#include <float.h>

#define NROWS  10000
#define INDIM  512
#define KSPLIT 384     // OpenBLAS sgemm kc split (Round-3 passing arithmetic — do not touch)
#define HID    128
#define NSTRIP 16
#define STRIPW 625
#define CHUNK  64
#define NCHUNK 10      // 10*64 = 640 >= 625
#define CAPS   64      // per-(row,strip) capacity: lambda~30.5 -> P(ovf)~8e-7/seg
#define RESC   32      // exactly-rescored per row
#define KOUT   14
#define ZPADR  10112   // zb pad rows (max A row 10111, max staged B row 10014)
#define GRIDX  79      // ceil(10000/128)
#define NBLK   1264    // GRIDX * NSTRIP -> 4 co-resident blocks/CU (32 waves, cap)
#define Z4TOT  25000000
#define Z4BLK  19779   // ceil(25e6 / 1264)
#define Z4CHK  1978    // ceil(Z4BLK / NCHUNK)
#define C_TAU  2.05f

using short8 = __attribute__((ext_vector_type(8))) short;
using f32x4  = __attribute__((ext_vector_type(4))) float;

// ---------------------------------------------------------------------------
// K1: bit-replicates numpy f32 (Round-3 passing arithmetic). feat rows staged
// once into LDS then broadcast-read (R15/R16-proven best variant). 4 rows per
// block (was 8): grid 2528 -> ~10 blocks/CU, 2x TLP to hide the serial FMA
// chains. FMA order per (row,h) unchanged (bit-exact).
// grid = 2528 x 128 (blocks 2500+ zero zb pad rows).
// ---------------------------------------------------------------------------
__global__ __launch_bounds__(128)
void k_projnorm(const float* __restrict__ feat, const float* __restrict__ W,
                const float* __restrict__ b, float* __restrict__ z32,
                __hip_bfloat16* __restrict__ zb) {
    const int h = threadIdx.x;
    const int row0 = blockIdx.x * 4;
    if (row0 >= NROWS) {                 // zero bf16 pad rows
#pragma unroll
        for (int r = 0; r < 4; ++r)
            if (row0 + r < ZPADR) zb[(size_t)(row0 + r) * HID + h] = __float2bfloat16(0.f);
        return;
    }
    __shared__ float fl[4][INDIM];       // 8 KB staged feat rows
#pragma unroll
    for (int i = 0; i < 4; ++i)
        *(float4*)&fl[i][h * 4] = *(const float4*)(feat + (size_t)(row0 + i) * INDIM + h * 4);
    __syncthreads();

    float accA[4], accB[4];
#pragma unroll
    for (int r = 0; r < 4; ++r) { accA[r] = 0.f; accB[r] = 0.f; }
#pragma unroll 4
    for (int k4 = 0; k4 < 96; ++k4) {    // k = 0..383 (chain A)
        const int k = k4 * 4;
        const float w0 = W[(k + 0) * HID + h];
        const float w1 = W[(k + 1) * HID + h];
        const float w2 = W[(k + 2) * HID + h];
        const float w3 = W[(k + 3) * HID + h];
#pragma unroll
        for (int r = 0; r < 4; ++r) {
            const float4 f = *(const float4*)&fl[r][k];
            accA[r] = fmaf(f.x, w0, accA[r]);
            accA[r] = fmaf(f.y, w1, accA[r]);
            accA[r] = fmaf(f.z, w2, accA[r]);
            accA[r] = fmaf(f.w, w3, accA[r]);
        }
    }
#pragma unroll 4
    for (int k4 = 96; k4 < 128; ++k4) {  // k = 384..511 (chain B)
        const int k = k4 * 4;
        const float w0 = W[(k + 0) * HID + h];
        const float w1 = W[(k + 1) * HID + h];
        const float w2 = W[(k + 2) * HID + h];
        const float w3 = W[(k + 3) * HID + h];
#pragma unroll
        for (int r = 0; r < 4; ++r) {
            const float4 f = *(const float4*)&fl[r][k];
            accB[r] = fmaf(f.x, w0, accB[r]);
            accB[r] = fmaf(f.y, w1, accB[r]);
            accB[r] = fmaf(f.z, w2, accB[r]);
            accB[r] = fmaf(f.w, w3, accB[r]);
        }
    }
    __shared__ float zl[4][HID];
    __shared__ float nrm[4];
    const float bh = b[h];
#pragma unroll
    for (int r = 0; r < 4; ++r)
        zl[r][h] = __fadd_rn(__fadd_rn(accA[r], accB[r]), bh);
    __syncthreads();
    if (h < 4) {
        float rr[8];
#pragma unroll
        for (int j = 0; j < 8; ++j) rr[j] = __fmul_rn(zl[h][j], zl[h][j]);
        for (int i = 8; i < HID; i += 8)
#pragma unroll
            for (int j = 0; j < 8; ++j)
                rr[j] = __fadd_rn(rr[j], __fmul_rn(zl[h][i + j], zl[h][i + j]));
        const float s = __fadd_rn(
            __fadd_rn(__fadd_rn(rr[0], rr[1]), __fadd_rn(rr[2], rr[3])),
            __fadd_rn(__fadd_rn(rr[4], rr[5]), __fadd_rn(rr[6], rr[7])));
        nrm[h] = fmaxf(__fsqrt_rn(s), 1e-12f);
    }
    __syncthreads();
#pragma unroll
    for (int r = 0; r < 4; ++r) {
        const float v = __fdiv_rn(zl[r][h], nrm[r]);
        z32[(size_t)(row0 + r) * HID + h] = v;
        zb [(size_t)(row0 + r) * HID + h] = __float2bfloat16(v);
    }
}

// ---------------------------------------------------------------------------
// K2: R15-proven LDS-staged 8-wave MFMA candidate generator, 16 strips,
// 4 co-resident blocks/CU (32 waves/CU cap). Double-buffered swizzled LDS,
// adaptive tau, LDS-counter append (CAPS=64), fused NT output zeroing.
// grid = (79, 16), block 512.   [R15 byte-identical]
// ---------------------------------------------------------------------------
__global__ __launch_bounds__(512)
void k_cand(const __hip_bfloat16* __restrict__ zbp, f32x4* __restrict__ out4,
            int* __restrict__ cnt4, unsigned int* __restrict__ list) {
    __shared__ ushort Bt[2][8192];      // 2 x 16 KB, swizzled [64 j][128 k] bf16
    __shared__ int lcnt[128];           // per-row append counters
    const char* zbb = (const char*)zbp;
    const int tid = threadIdx.x, lane = tid & 63, wid = tid >> 6;
    const int row0 = blockIdx.x * 128;
    const int strip = blockIdx.y;
    const int jbase = strip * STRIPW;
    const int bid = strip * GRIDX + blockIdx.x;
    const int row_g = row0 + wid * 16 + (lane & 15);
    const int rloc  = wid * 16 + (lane & 15);
    const int swz = (lane & 7) << 4;

    if (tid < 128) lcnt[tid] = 0;

    // A fragments (used as mfma B-operand): lane holds z[row_g][(l>>4)*8+ks*32..+8]
    short8 afr[4];
    {
        const char* ap = zbb + (size_t)row_g * 256 + ((lane >> 4) * 16);
        afr[0] = *(const short8*)(ap);
        afr[1] = *(const short8*)(ap + 64);
        afr[2] = *(const short8*)(ap + 128);
        afr[3] = *(const short8*)(ap + 192);
    }

    // staging map: thread stages 32 B of the 16 KB chunk
    const int sjl = tid >> 3;           // local j row 0..63
    const int sir = (tid & 7) * 32;     // in-row byte 0..224
    const int sw0 = sir ^ ((sjl & 7) << 4);
    const int sw1 = (sir + 16) ^ ((sjl & 7) << 4);

    // prologue: stage chunk 0 -> buf 0
    {
        const char* src = zbb + (size_t)(jbase + sjl) * 256 + sir;
        const uint4 d0 = *(const uint4*)(src);
        const uint4 d1 = *(const uint4*)(src + 16);
        char* dst = (char*)Bt[0] + (size_t)sjl * 256;
        *(uint4*)(dst + sw0) = d0;
        *(uint4*)(dst + sw1) = d1;
    }
    __syncthreads();

    const size_t zb0 = (size_t)bid * Z4BLK;
    int zlen = Z4TOT - (int)zb0; if (zlen > Z4BLK) zlen = Z4BLK;
    f32x4* zp = out4 + zb0;
    const f32x4 zero4 = {0.f, 0.f, 0.f, 0.f};

    float ss = 0.f;   // row-pooled sum of squared sims (n = 64*c samples)

#pragma unroll 1
    for (int c = 0; c < NCHUNK; ++c) {
        const int jc = c * CHUNK;
        const char* cur = (const char*)Bt[c & 1];

        // issue next-chunk global loads early
        uint4 st0, st1;
        const bool nx = (c + 1 < NCHUNK);
        if (nx) {
            const char* src = zbb + (size_t)(jbase + jc + CHUNK + sjl) * 256 + sir;
            st0 = *(const uint4*)(src);
            st1 = *(const uint4*)(src + 16);
        }

        // fused output zeroing slice (NT streaming; drains under compute)
        {
            const int z0 = c * Z4CHK;
            int ze = z0 + Z4CHK; if (ze > zlen) ze = zlen;
            for (int i = z0 + tid; i < ze; i += 512)
                __builtin_nontemporal_store(zero4, zp + i);
        }

        // adaptive threshold for this chunk
        float tau;
        if (c == 0) tau = 0.10f;
        else {
            const float n = 64.f * (float)c;
            const float w = 1.f - 3.f * __frsqrt_rn(2.f * n);
            tau = fmaxf(C_TAU * w * __fsqrt_rn(ss / n), 0.08f);
        }

        // 16 mfma, swapped operands: lane owns output row row_g
        f32x4 acc[4];
#pragma unroll
        for (int t = 0; t < 4; ++t) {
            acc[t] = (f32x4){0.f, 0.f, 0.f, 0.f};
            const char* rp = cur + (size_t)(t * 16 + (lane & 15)) * 256;
#pragma unroll
            for (int ks = 0; ks < 4; ++ks) {
                const short8 bfr = *(const short8*)(rp + ((ks * 64 + (lane >> 4) * 16) ^ swz));
                acc[t] = __builtin_amdgcn_mfma_f32_16x16x32_bf16(bfr, afr[ks], acc[t], 0, 0, 0);
            }
        }

        // sigma accumulation + LDS-counter append (fire-and-forget store)
        float ssl = 0.f;
#pragma unroll
        for (int t = 0; t < 4; ++t) {
#pragma unroll
            for (int r = 0; r < 4; ++r) {
                const float val = acc[t][r];
                const int js = jc + t * 16 + ((lane >> 4) << 2) + r;
                const int jg = jbase + js;
                const bool ok = (js < STRIPW) && (jg != row_g);
                ssl += ok ? val * val : 0.f;
                if (ok && val > tau) {
                    const unsigned int u = __builtin_bit_cast(unsigned int, val);
                    const unsigned int pk = (((u + 0x8000u) >> 16) << 16) | (unsigned int)jg;
                    const int pos = atomicAdd(&lcnt[rloc], 1);
                    if (pos < CAPS)
                        list[((size_t)row_g * NSTRIP + strip) * CAPS + pos] = pk;
                }
            }
        }
        ssl += __shfl_xor(ssl, 16, 64);   // pool over the row's 4 lanes
        ssl += __shfl_xor(ssl, 32, 64);
        ss += ssl;

        // write staged regs -> other buffer
        if (nx) {
            char* wb = (char*)Bt[(c + 1) & 1] + (size_t)sjl * 256;
            *(uint4*)(wb + sw0) = st0;
            *(uint4*)(wb + sw1) = st1;
        }
        __syncthreads();
    }

    // flush per-(row, strip) counts (this block is the exclusive owner)
    if (tid < 128) {
        const int row = row0 + tid;
        if (row < NROWS) cnt4[row * NSTRIP + strip] = lcnt[tid];
    }
}

// ---------------------------------------------------------------------------
// K3: approx-top-32 of the 16 per-strip segments (packed bf16|idx keys,
// 16 regs/lane = 1024 slots exactly), exact rescore of those 32 with the
// bit-exact sequential f32 FMA chain, exact top-14 by (value desc, idx asc),
// scatter. Rows pre-zeroed by K2. grid = 2500 (4 rows/block, 1 wave/row).
// [R15 byte-identical]
// ---------------------------------------------------------------------------
#define CEK(a, b) { const unsigned int x_ = k[a], y_ = k[b]; \
    k[a] = x_ > y_ ? x_ : y_; k[b] = x_ > y_ ? y_ : x_; }

__global__ __launch_bounds__(256)
void k_select(const float* __restrict__ z32, const int* __restrict__ cnt4,
              const unsigned int* __restrict__ list, float* __restrict__ out) {
    __shared__ float zr[4][HID];
    const int tid = threadIdx.x, wid = tid >> 6, lane = tid & 63;
    const int row = blockIdx.x * 4 + wid;

    *(float2*)&zr[wid][lane * 2] = *(const float2*)(z32 + (size_t)row * HID + lane * 2);
    __syncthreads();

    unsigned int k[16];
#pragma unroll
    for (int t = 0; t < 16; ++t) {
        const int p = t * 64 + lane;          // 0..1023
        const int seg = p >> 6;               // p / CAPS (CAPS = 64)
        const int off = p & 63;
        int cn = cnt4[row * NSTRIP + seg]; if (cn > CAPS) cn = CAPS;
        k[t] = (off < cn) ? list[((size_t)row * NSTRIP + seg) * CAPS + off] : 0u;
    }

    // bitonic sort-16 descending (static indices, sentinel 0)
#pragma unroll
    for (int size = 2; size <= 16; size <<= 1) {
#pragma unroll
        for (int stride = size >> 1; stride > 0; stride >>= 1) {
#pragma unroll
            for (int i = 0; i < 16; ++i) {
                const int j = i ^ stride;
                if (j > i) {
                    if ((i & size) == 0) { CEK(i, j); } else { CEK(j, i); }
                }
            }
        }
    }

    // 32 pops by packed key (keys unique: idx in low bits); lane t keeps pop t
    unsigned int win = 0u;
#pragma unroll 1
    for (int t = 0; t < RESC; ++t) {
        unsigned int m = k[0];
#pragma unroll
        for (int msk = 1; msk <= 32; msk <<= 1) {
            const unsigned int o = (unsigned int)__shfl_xor((int)m, msk, 64);
            m = o > m ? o : m;
        }
        if (lane == t) win = m;
        if (k[0] == m && m != 0u) {
#pragma unroll
            for (int s = 0; s < 15; ++s) k[s] = k[s + 1];
            k[15] = 0u;
        }
    }

    // exact rescore (bit-exact Round-3 chain) of the 32 winners
    float ex = -INFINITY; int idx = 0x7fffffff;
    const bool act = (lane < RESC) && (win != 0u);
    if (act) {
        idx = (int)(win & 0xFFFFu);
        const float* p = z32 + (size_t)idx * HID;
        float a = 0.f;
#pragma unroll
        for (int k4 = 0; k4 < 32; ++k4) {   // strict k-ascending chain
            const float4 bb = *(const float4*)(p + k4 * 4);
            const float4 zz = *(const float4*)&zr[wid][k4 * 4];
            a = fmaf(zz.x, bb.x, a);
            a = fmaf(zz.y, bb.y, a);
            a = fmaf(zz.z, bb.z, a);
            a = fmaf(zz.w, bb.w, a);
        }
        ex = a;
    }

    bool alive = act;
#pragma unroll 1
    for (int t = 0; t < KOUT; ++t) {
        float mv = alive ? ex : -INFINITY;
        int   mi = alive ? idx : 0x7fffffff;
#pragma unroll
        for (int msk = 1; msk <= 32; msk <<= 1) {
            const float ov = __shfl_xor(mv, msk, 64);
            const int   oj = __shfl_xor(mi, msk, 64);
            const bool take = (ov > mv) || (ov == mv && oj < mi);
            mv = take ? ov : mv; mi = take ? oj : mi;
        }
        if (alive && idx == mi) {
            out[(size_t)row * NROWS + mi] = ex;
            alive = false;
        }
    }
}

// ---------------------------------------------------------------------------
extern "C" void kernel_launch(void* const* d_in, const int* in_sizes, int n_in,
                              void* d_out, int out_size, void* d_ws, size_t ws_size,
                              hipStream_t stream) {
    const float* feat = (const float*)d_in[0];
    const float* W    = (const float*)d_in[1];
    const float* b    = (const float*)d_in[2];
    float* out = (float*)d_out;

    char* ws = (char*)d_ws;
    float*          z32  = (float*)ws;                          //  5,120,000 B
    __hip_bfloat16* zb   = (__hip_bfloat16*)(ws + 5120000);     //  2,588,672 B (10112x256)
    int*            cnt4 = (int*)(ws + 7708672);                //    640,000 B (10000x16)
    unsigned int*   lst  = (unsigned int*)(ws + 8348672);       // 40,960,000 B (10000x16x64x4)

    hipLaunchKernelGGL(k_projnorm, dim3(2528),          dim3(128), 0, stream, feat, W, b, z32, zb);
    hipLaunchKernelGGL(k_cand,     dim3(GRIDX, NSTRIP), dim3(512), 0, stream, zb, (f32x4*)out, cnt4, lst);
    hipLaunchKernelGGL(k_select,   dim3(2500),          dim3(256), 0, stream, z32, cnt4, lst, out);
}

// Round 19
// 204.941 us; speedup vs baseline: 1.1854x; 1.0097x over previous
//
#include <hip/hip_runtime.h>
#include <hip/hip_bf16.h>
#include <math.h>
#include <float.h>

#define NROWS  10000
#define INDIM  512
#define KSPLIT 384     // OpenBLAS sgemm kc split (Round-3 passing arithmetic — do not touch)
#define HID    128
#define NSTRIP 16
#define STRIPW 625
#define CHUNK  64
#define NCHUNK 10      // 10*64 = 640 >= 625
#define CAPS   64      // per-(row,strip) capacity: lambda~30.5 -> P(ovf)~8e-7/seg
#define RESC   32      // exactly-rescored per row
#define KOUT   14
#define ZPADR  10112   // zb pad rows (max A row 10111, max staged B row 10014)
#define GRIDX  79      // ceil(10000/128)
#define NBLK   1264    // GRIDX * NSTRIP -> 4 co-resident blocks/CU (32 waves, cap)
#define Z4TOT  25000000
#define Z4BLK  19779   // ceil(25e6 / 1264)
#define Z4CHK  1978    // ceil(Z4BLK / NCHUNK)
#define C_TAU  2.05f

using short8 = __attribute__((ext_vector_type(8))) short;
using f32x4  = __attribute__((ext_vector_type(4))) float;

// LDS-only barrier: all cross-wave data in k_cand flows through LDS
// (Bt ds_writes + lcnt DS-atomics, both counted by lgkmcnt). Skips the
// vmcnt(0) drain __syncthreads imposes — NT zero-stores and prefetch
// loads stay in flight across the barrier. [helper field-proven in R12]
__device__ __forceinline__ void lds_barrier() {
    asm volatile("s_waitcnt lgkmcnt(0)" ::: "memory");
    __builtin_amdgcn_s_barrier();
}

// ---------------------------------------------------------------------------
// K1: bit-replicates numpy f32 (Round-3 passing arithmetic). feat rows staged
// once into LDS then broadcast-read. 4 rows/block, grid 2528 -> ~10 blocks/CU
// (R18-proven: TLP hides the serial FMA chains). FMA order unchanged.
// grid = 2528 x 128 (blocks 2500+ zero zb pad rows).  [R18 byte-identical]
// ---------------------------------------------------------------------------
__global__ __launch_bounds__(128)
void k_projnorm(const float* __restrict__ feat, const float* __restrict__ W,
                const float* __restrict__ b, float* __restrict__ z32,
                __hip_bfloat16* __restrict__ zb) {
    const int h = threadIdx.x;
    const int row0 = blockIdx.x * 4;
    if (row0 >= NROWS) {                 // zero bf16 pad rows
#pragma unroll
        for (int r = 0; r < 4; ++r)
            if (row0 + r < ZPADR) zb[(size_t)(row0 + r) * HID + h] = __float2bfloat16(0.f);
        return;
    }
    __shared__ float fl[4][INDIM];       // 8 KB staged feat rows
#pragma unroll
    for (int i = 0; i < 4; ++i)
        *(float4*)&fl[i][h * 4] = *(const float4*)(feat + (size_t)(row0 + i) * INDIM + h * 4);
    __syncthreads();

    float accA[4], accB[4];
#pragma unroll
    for (int r = 0; r < 4; ++r) { accA[r] = 0.f; accB[r] = 0.f; }
#pragma unroll 4
    for (int k4 = 0; k4 < 96; ++k4) {    // k = 0..383 (chain A)
        const int k = k4 * 4;
        const float w0 = W[(k + 0) * HID + h];
        const float w1 = W[(k + 1) * HID + h];
        const float w2 = W[(k + 2) * HID + h];
        const float w3 = W[(k + 3) * HID + h];
#pragma unroll
        for (int r = 0; r < 4; ++r) {
            const float4 f = *(const float4*)&fl[r][k];
            accA[r] = fmaf(f.x, w0, accA[r]);
            accA[r] = fmaf(f.y, w1, accA[r]);
            accA[r] = fmaf(f.z, w2, accA[r]);
            accA[r] = fmaf(f.w, w3, accA[r]);
        }
    }
#pragma unroll 4
    for (int k4 = 96; k4 < 128; ++k4) {  // k = 384..511 (chain B)
        const int k = k4 * 4;
        const float w0 = W[(k + 0) * HID + h];
        const float w1 = W[(k + 1) * HID + h];
        const float w2 = W[(k + 2) * HID + h];
        const float w3 = W[(k + 3) * HID + h];
#pragma unroll
        for (int r = 0; r < 4; ++r) {
            const float4 f = *(const float4*)&fl[r][k];
            accB[r] = fmaf(f.x, w0, accB[r]);
            accB[r] = fmaf(f.y, w1, accB[r]);
            accB[r] = fmaf(f.z, w2, accB[r]);
            accB[r] = fmaf(f.w, w3, accB[r]);
        }
    }
    __shared__ float zl[4][HID];
    __shared__ float nrm[4];
    const float bh = b[h];
#pragma unroll
    for (int r = 0; r < 4; ++r)
        zl[r][h] = __fadd_rn(__fadd_rn(accA[r], accB[r]), bh);
    __syncthreads();
    if (h < 4) {
        float rr[8];
#pragma unroll
        for (int j = 0; j < 8; ++j) rr[j] = __fmul_rn(zl[h][j], zl[h][j]);
        for (int i = 8; i < HID; i += 8)
#pragma unroll
            for (int j = 0; j < 8; ++j)
                rr[j] = __fadd_rn(rr[j], __fmul_rn(zl[h][i + j], zl[h][i + j]));
        const float s = __fadd_rn(
            __fadd_rn(__fadd_rn(rr[0], rr[1]), __fadd_rn(rr[2], rr[3])),
            __fadd_rn(__fadd_rn(rr[4], rr[5]), __fadd_rn(rr[6], rr[7])));
        nrm[h] = fmaxf(__fsqrt_rn(s), 1e-12f);
    }
    __syncthreads();
#pragma unroll
    for (int r = 0; r < 4; ++r) {
        const float v = __fdiv_rn(zl[r][h], nrm[r]);
        z32[(size_t)(row0 + r) * HID + h] = v;
        zb [(size_t)(row0 + r) * HID + h] = __float2bfloat16(v);
    }
}

// ---------------------------------------------------------------------------
// K2: R15-proven LDS-staged 8-wave MFMA candidate generator, 16 strips,
// 4 co-resident blocks/CU. Double-buffered swizzled LDS, adaptive tau,
// LDS-counter append (CAPS=64), fused NT output zeroing. SINGLE CHANGE vs
// R18: lgkm-only barriers (no vmcnt(0) drain of NT stores / prefetch).
// grid = (79, 16), block 512.
// ---------------------------------------------------------------------------
__global__ __launch_bounds__(512)
void k_cand(const __hip_bfloat16* __restrict__ zbp, f32x4* __restrict__ out4,
            int* __restrict__ cnt4, unsigned int* __restrict__ list) {
    __shared__ ushort Bt[2][8192];      // 2 x 16 KB, swizzled [64 j][128 k] bf16
    __shared__ int lcnt[128];           // per-row append counters
    const char* zbb = (const char*)zbp;
    const int tid = threadIdx.x, lane = tid & 63, wid = tid >> 6;
    const int row0 = blockIdx.x * 128;
    const int strip = blockIdx.y;
    const int jbase = strip * STRIPW;
    const int bid = strip * GRIDX + blockIdx.x;
    const int row_g = row0 + wid * 16 + (lane & 15);
    const int rloc  = wid * 16 + (lane & 15);
    const int swz = (lane & 7) << 4;

    if (tid < 128) lcnt[tid] = 0;

    // A fragments (used as mfma B-operand): lane holds z[row_g][(l>>4)*8+ks*32..+8]
    short8 afr[4];
    {
        const char* ap = zbb + (size_t)row_g * 256 + ((lane >> 4) * 16);
        afr[0] = *(const short8*)(ap);
        afr[1] = *(const short8*)(ap + 64);
        afr[2] = *(const short8*)(ap + 128);
        afr[3] = *(const short8*)(ap + 192);
    }

    // staging map: thread stages 32 B of the 16 KB chunk
    const int sjl = tid >> 3;           // local j row 0..63
    const int sir = (tid & 7) * 32;     // in-row byte 0..224
    const int sw0 = sir ^ ((sjl & 7) << 4);
    const int sw1 = (sir + 16) ^ ((sjl & 7) << 4);

    // prologue: stage chunk 0 -> buf 0
    {
        const char* src = zbb + (size_t)(jbase + sjl) * 256 + sir;
        const uint4 d0 = *(const uint4*)(src);
        const uint4 d1 = *(const uint4*)(src + 16);
        char* dst = (char*)Bt[0] + (size_t)sjl * 256;
        *(uint4*)(dst + sw0) = d0;
        *(uint4*)(dst + sw1) = d1;
    }
    lds_barrier();

    const size_t zb0 = (size_t)bid * Z4BLK;
    int zlen = Z4TOT - (int)zb0; if (zlen > Z4BLK) zlen = Z4BLK;
    f32x4* zp = out4 + zb0;
    const f32x4 zero4 = {0.f, 0.f, 0.f, 0.f};

    float ss = 0.f;   // row-pooled sum of squared sims (n = 64*c samples)

#pragma unroll 1
    for (int c = 0; c < NCHUNK; ++c) {
        const int jc = c * CHUNK;
        const char* cur = (const char*)Bt[c & 1];

        // issue next-chunk global loads early
        uint4 st0, st1;
        const bool nx = (c + 1 < NCHUNK);
        if (nx) {
            const char* src = zbb + (size_t)(jbase + jc + CHUNK + sjl) * 256 + sir;
            st0 = *(const uint4*)(src);
            st1 = *(const uint4*)(src + 16);
        }

        // fused output zeroing slice (NT streaming; never drained in-loop)
        {
            const int z0 = c * Z4CHK;
            int ze = z0 + Z4CHK; if (ze > zlen) ze = zlen;
            for (int i = z0 + tid; i < ze; i += 512)
                __builtin_nontemporal_store(zero4, zp + i);
        }

        // adaptive threshold for this chunk
        float tau;
        if (c == 0) tau = 0.10f;
        else {
            const float n = 64.f * (float)c;
            const float w = 1.f - 3.f * __frsqrt_rn(2.f * n);
            tau = fmaxf(C_TAU * w * __fsqrt_rn(ss / n), 0.08f);
        }

        // 16 mfma, swapped operands: lane owns output row row_g
        f32x4 acc[4];
#pragma unroll
        for (int t = 0; t < 4; ++t) {
            acc[t] = (f32x4){0.f, 0.f, 0.f, 0.f};
            const char* rp = cur + (size_t)(t * 16 + (lane & 15)) * 256;
#pragma unroll
            for (int ks = 0; ks < 4; ++ks) {
                const short8 bfr = *(const short8*)(rp + ((ks * 64 + (lane >> 4) * 16) ^ swz));
                acc[t] = __builtin_amdgcn_mfma_f32_16x16x32_bf16(bfr, afr[ks], acc[t], 0, 0, 0);
            }
        }

        // sigma accumulation + LDS-counter append (fire-and-forget store)
        float ssl = 0.f;
#pragma unroll
        for (int t = 0; t < 4; ++t) {
#pragma unroll
            for (int r = 0; r < 4; ++r) {
                const float val = acc[t][r];
                const int js = jc + t * 16 + ((lane >> 4) << 2) + r;
                const int jg = jbase + js;
                const bool ok = (js < STRIPW) && (jg != row_g);
                ssl += ok ? val * val : 0.f;
                if (ok && val > tau) {
                    const unsigned int u = __builtin_bit_cast(unsigned int, val);
                    const unsigned int pk = (((u + 0x8000u) >> 16) << 16) | (unsigned int)jg;
                    const int pos = atomicAdd(&lcnt[rloc], 1);
                    if (pos < CAPS)
                        list[((size_t)row_g * NSTRIP + strip) * CAPS + pos] = pk;
                }
            }
        }
        ssl += __shfl_xor(ssl, 16, 64);   // pool over the row's 4 lanes
        ssl += __shfl_xor(ssl, 32, 64);
        ss += ssl;

        // write staged regs -> other buffer
        if (nx) {
            char* wb = (char*)Bt[(c + 1) & 1] + (size_t)sjl * 256;
            *(uint4*)(wb + sw0) = st0;
            *(uint4*)(wb + sw1) = st1;
        }
        lds_barrier();
    }

    // flush per-(row, strip) counts (this block is the exclusive owner)
    if (tid < 128) {
        const int row = row0 + tid;
        if (row < NROWS) cnt4[row * NSTRIP + strip] = lcnt[tid];
    }
}

// ---------------------------------------------------------------------------
// K3: approx-top-32 of the 16 per-strip segments (packed bf16|idx keys,
// 16 regs/lane = 1024 slots exactly), exact rescore of those 32 with the
// bit-exact sequential f32 FMA chain, exact top-14 by (value desc, idx asc),
// scatter. Rows pre-zeroed by K2. grid = 2500 (4 rows/block, 1 wave/row).
// [R15/R18 byte-identical]
// ---------------------------------------------------------------------------
#define CEK(a, b) { const unsigned int x_ = k[a], y_ = k[b]; \
    k[a] = x_ > y_ ? x_ : y_; k[b] = x_ > y_ ? y_ : x_; }

__global__ __launch_bounds__(256)
void k_select(const float* __restrict__ z32, const int* __restrict__ cnt4,
              const unsigned int* __restrict__ list, float* __restrict__ out) {
    __shared__ float zr[4][HID];
    const int tid = threadIdx.x, wid = tid >> 6, lane = tid & 63;
    const int row = blockIdx.x * 4 + wid;

    *(float2*)&zr[wid][lane * 2] = *(const float2*)(z32 + (size_t)row * HID + lane * 2);
    __syncthreads();

    unsigned int k[16];
#pragma unroll
    for (int t = 0; t < 16; ++t) {
        const int p = t * 64 + lane;          // 0..1023
        const int seg = p >> 6;               // p / CAPS (CAPS = 64)
        const int off = p & 63;
        int cn = cnt4[row * NSTRIP + seg]; if (cn > CAPS) cn = CAPS;
        k[t] = (off < cn) ? list[((size_t)row * NSTRIP + seg) * CAPS + off] : 0u;
    }

    // bitonic sort-16 descending (static indices, sentinel 0)
#pragma unroll
    for (int size = 2; size <= 16; size <<= 1) {
#pragma unroll
        for (int stride = size >> 1; stride > 0; stride >>= 1) {
#pragma unroll
            for (int i = 0; i < 16; ++i) {
                const int j = i ^ stride;
                if (j > i) {
                    if ((i & size) == 0) { CEK(i, j); } else { CEK(j, i); }
                }
            }
        }
    }

    // 32 pops by packed key (keys unique: idx in low bits); lane t keeps pop t
    unsigned int win = 0u;
#pragma unroll 1
    for (int t = 0; t < RESC; ++t) {
        unsigned int m = k[0];
#pragma unroll
        for (int msk = 1; msk <= 32; msk <<= 1) {
            const unsigned int o = (unsigned int)__shfl_xor((int)m, msk, 64);
            m = o > m ? o : m;
        }
        if (lane == t) win = m;
        if (k[0] == m && m != 0u) {
#pragma unroll
            for (int s = 0; s < 15; ++s) k[s] = k[s + 1];
            k[15] = 0u;
        }
    }

    // exact rescore (bit-exact Round-3 chain) of the 32 winners
    float ex = -INFINITY; int idx = 0x7fffffff;
    const bool act = (lane < RESC) && (win != 0u);
    if (act) {
        idx = (int)(win & 0xFFFFu);
        const float* p = z32 + (size_t)idx * HID;
        float a = 0.f;
#pragma unroll
        for (int k4 = 0; k4 < 32; ++k4) {   // strict k-ascending chain
            const float4 bb = *(const float4*)(p + k4 * 4);
            const float4 zz = *(const float4*)&zr[wid][k4 * 4];
            a = fmaf(zz.x, bb.x, a);
            a = fmaf(zz.y, bb.y, a);
            a = fmaf(zz.z, bb.z, a);
            a = fmaf(zz.w, bb.w, a);
        }
        ex = a;
    }

    bool alive = act;
#pragma unroll 1
    for (int t = 0; t < KOUT; ++t) {
        float mv = alive ? ex : -INFINITY;
        int   mi = alive ? idx : 0x7fffffff;
#pragma unroll
        for (int msk = 1; msk <= 32; msk <<= 1) {
            const float ov = __shfl_xor(mv, msk, 64);
            const int   oj = __shfl_xor(mi, msk, 64);
            const bool take = (ov > mv) || (ov == mv && oj < mi);
            mv = take ? ov : mv; mi = take ? oj : mi;
        }
        if (alive && idx == mi) {
            out[(size_t)row * NROWS + mi] = ex;
            alive = false;
        }
    }
}

// ---------------------------------------------------------------------------
extern "C" void kernel_launch(void* const* d_in, const int* in_sizes, int n_in,
                              void* d_out, int out_size, void* d_ws, size_t ws_size,
                              hipStream_t stream) {
    const float* feat = (const float*)d_in[0];
    const float* W    = (const float*)d_in[1];
    const float* b    = (const float*)d_in[2];
    float* out = (float*)d_out;

    char* ws = (char*)d_ws;
    float*          z32  = (float*)ws;                          //  5,120,000 B
    __hip_bfloat16* zb   = (__hip_bfloat16*)(ws + 5120000);     //  2,588,672 B (10112x256)
    int*            cnt4 = (int*)(ws + 7708672);                //    640,000 B (10000x16)
    unsigned int*   lst  = (unsigned int*)(ws + 8348672);       // 40,960,000 B (10000x16x64x4)

    hipLaunchKernelGGL(k_projnorm, dim3(2528),          dim3(128), 0, stream, feat, W, b, z32, zb);
    hipLaunchKernelGGL(k_cand,     dim3(GRIDX, NSTRIP), dim3(512), 0, stream, zb, (f32x4*)out, cnt4, lst);
    hipLaunchKernelGGL(k_select,   dim3(2500),          dim3(256), 0, stream, z32, cnt4, lst, out);
}

// Round 20
// 204.103 us; speedup vs baseline: 1.1902x; 1.0041x over previous
//
#include <hip/hip_runtime.h>
#include <hip/hip_bf16.h>
#include <math.h>
#include <float.h>

#define NROWS  10000
#define INDIM  512
#define KSPLIT 384     // OpenBLAS sgemm kc split (Round-3 passing arithmetic — do not touch)
#define HID    128
#define NSTRIP 16
#define STRIPW 625
#define CHUNK  64
#define NCHUNK 10      // 10*64 = 640 >= 625
#define CAPS   64      // per-(row,strip) capacity: lambda~30.5 -> P(ovf)~8e-7/seg
#define RESC   32      // exactly-rescored per row
#define KOUT   14
#define ZPADR  10112   // zb pad rows (max A row 10111, max staged B row 10014)
#define GRIDX  79      // ceil(10000/128)
#define NBLK   1264    // GRIDX * NSTRIP -> 4 co-resident blocks/CU (32 waves, cap)
#define Z4TOT  25000000
#define Z4BLK  19779   // ceil(25e6 / 1264)
#define Z4CHK  1978    // ceil(Z4BLK / NCHUNK)
#define C_TAU  2.05f

using short8 = __attribute__((ext_vector_type(8))) short;
using f32x4  = __attribute__((ext_vector_type(4))) float;

// LDS-only barrier: all cross-wave data in k_cand flows through LDS
// (Bt ds_writes + lcnt DS-atomics, both counted by lgkmcnt). Skips the
// vmcnt(0) drain __syncthreads imposes. [R19-proven]
__device__ __forceinline__ void lds_barrier() {
    asm volatile("s_waitcnt lgkmcnt(0)" ::: "memory");
    __builtin_amdgcn_s_barrier();
}

// ---------------------------------------------------------------------------
// K1: bit-replicates numpy f32 (Round-3 passing arithmetic). feat rows staged
// once into LDS then broadcast-read. 4 rows/block, grid 2528 -> ~10 blocks/CU.
// [R18 byte-identical]
// ---------------------------------------------------------------------------
__global__ __launch_bounds__(128)
void k_projnorm(const float* __restrict__ feat, const float* __restrict__ W,
                const float* __restrict__ b, float* __restrict__ z32,
                __hip_bfloat16* __restrict__ zb) {
    const int h = threadIdx.x;
    const int row0 = blockIdx.x * 4;
    if (row0 >= NROWS) {                 // zero bf16 pad rows
#pragma unroll
        for (int r = 0; r < 4; ++r)
            if (row0 + r < ZPADR) zb[(size_t)(row0 + r) * HID + h] = __float2bfloat16(0.f);
        return;
    }
    __shared__ float fl[4][INDIM];       // 8 KB staged feat rows
#pragma unroll
    for (int i = 0; i < 4; ++i)
        *(float4*)&fl[i][h * 4] = *(const float4*)(feat + (size_t)(row0 + i) * INDIM + h * 4);
    __syncthreads();

    float accA[4], accB[4];
#pragma unroll
    for (int r = 0; r < 4; ++r) { accA[r] = 0.f; accB[r] = 0.f; }
#pragma unroll 4
    for (int k4 = 0; k4 < 96; ++k4) {    // k = 0..383 (chain A)
        const int k = k4 * 4;
        const float w0 = W[(k + 0) * HID + h];
        const float w1 = W[(k + 1) * HID + h];
        const float w2 = W[(k + 2) * HID + h];
        const float w3 = W[(k + 3) * HID + h];
#pragma unroll
        for (int r = 0; r < 4; ++r) {
            const float4 f = *(const float4*)&fl[r][k];
            accA[r] = fmaf(f.x, w0, accA[r]);
            accA[r] = fmaf(f.y, w1, accA[r]);
            accA[r] = fmaf(f.z, w2, accA[r]);
            accA[r] = fmaf(f.w, w3, accA[r]);
        }
    }
#pragma unroll 4
    for (int k4 = 96; k4 < 128; ++k4) {  // k = 384..511 (chain B)
        const int k = k4 * 4;
        const float w0 = W[(k + 0) * HID + h];
        const float w1 = W[(k + 1) * HID + h];
        const float w2 = W[(k + 2) * HID + h];
        const float w3 = W[(k + 3) * HID + h];
#pragma unroll
        for (int r = 0; r < 4; ++r) {
            const float4 f = *(const float4*)&fl[r][k];
            accB[r] = fmaf(f.x, w0, accB[r]);
            accB[r] = fmaf(f.y, w1, accB[r]);
            accB[r] = fmaf(f.z, w2, accB[r]);
            accB[r] = fmaf(f.w, w3, accB[r]);
        }
    }
    __shared__ float zl[4][HID];
    __shared__ float nrm[4];
    const float bh = b[h];
#pragma unroll
    for (int r = 0; r < 4; ++r)
        zl[r][h] = __fadd_rn(__fadd_rn(accA[r], accB[r]), bh);
    __syncthreads();
    if (h < 4) {
        float rr[8];
#pragma unroll
        for (int j = 0; j < 8; ++j) rr[j] = __fmul_rn(zl[h][j], zl[h][j]);
        for (int i = 8; i < HID; i += 8)
#pragma unroll
            for (int j = 0; j < 8; ++j)
                rr[j] = __fadd_rn(rr[j], __fmul_rn(zl[h][i + j], zl[h][i + j]));
        const float s = __fadd_rn(
            __fadd_rn(__fadd_rn(rr[0], rr[1]), __fadd_rn(rr[2], rr[3])),
            __fadd_rn(__fadd_rn(rr[4], rr[5]), __fadd_rn(rr[6], rr[7])));
        nrm[h] = fmaxf(__fsqrt_rn(s), 1e-12f);
    }
    __syncthreads();
#pragma unroll
    for (int r = 0; r < 4; ++r) {
        const float v = __fdiv_rn(zl[r][h], nrm[r]);
        z32[(size_t)(row0 + r) * HID + h] = v;
        zb [(size_t)(row0 + r) * HID + h] = __float2bfloat16(v);
    }
}

// ---------------------------------------------------------------------------
// K2: R15-structure LDS-staged 8-wave MFMA candidate generator, lgkm-only
// barriers (R19). SINGLE CHANGE vs R19: aggregated append — ONE LDS atomic
// per lane per chunk (pass-mask + count in VALU, reservation, fire-and-forget
// global stores) instead of ~16 serialized same-address atomic bodies on the
// lgkm barrier path. grid = (79, 16), block 512.
// ---------------------------------------------------------------------------
__global__ __launch_bounds__(512)
void k_cand(const __hip_bfloat16* __restrict__ zbp, f32x4* __restrict__ out4,
            int* __restrict__ cnt4, unsigned int* __restrict__ list) {
    __shared__ ushort Bt[2][8192];      // 2 x 16 KB, swizzled [64 j][128 k] bf16
    __shared__ int lcnt[128];           // per-row append counters
    const char* zbb = (const char*)zbp;
    const int tid = threadIdx.x, lane = tid & 63, wid = tid >> 6;
    const int row0 = blockIdx.x * 128;
    const int strip = blockIdx.y;
    const int jbase = strip * STRIPW;
    const int bid = strip * GRIDX + blockIdx.x;
    const int row_g = row0 + wid * 16 + (lane & 15);
    const int rloc  = wid * 16 + (lane & 15);
    const int swz = (lane & 7) << 4;
    const size_t segbase = ((size_t)row_g * NSTRIP + strip) * CAPS;

    if (tid < 128) lcnt[tid] = 0;

    // A fragments (used as mfma B-operand): lane holds z[row_g][(l>>4)*8+ks*32..+8]
    short8 afr[4];
    {
        const char* ap = zbb + (size_t)row_g * 256 + ((lane >> 4) * 16);
        afr[0] = *(const short8*)(ap);
        afr[1] = *(const short8*)(ap + 64);
        afr[2] = *(const short8*)(ap + 128);
        afr[3] = *(const short8*)(ap + 192);
    }

    // staging map: thread stages 32 B of the 16 KB chunk
    const int sjl = tid >> 3;           // local j row 0..63
    const int sir = (tid & 7) * 32;     // in-row byte 0..224
    const int sw0 = sir ^ ((sjl & 7) << 4);
    const int sw1 = (sir + 16) ^ ((sjl & 7) << 4);

    // prologue: stage chunk 0 -> buf 0
    {
        const char* src = zbb + (size_t)(jbase + sjl) * 256 + sir;
        const uint4 d0 = *(const uint4*)(src);
        const uint4 d1 = *(const uint4*)(src + 16);
        char* dst = (char*)Bt[0] + (size_t)sjl * 256;
        *(uint4*)(dst + sw0) = d0;
        *(uint4*)(dst + sw1) = d1;
    }
    lds_barrier();

    const size_t zb0 = (size_t)bid * Z4BLK;
    int zlen = Z4TOT - (int)zb0; if (zlen > Z4BLK) zlen = Z4BLK;
    f32x4* zp = out4 + zb0;
    const f32x4 zero4 = {0.f, 0.f, 0.f, 0.f};

    float ss = 0.f;   // row-pooled sum of squared sims (n = 64*c samples)

#pragma unroll 1
    for (int c = 0; c < NCHUNK; ++c) {
        const int jc = c * CHUNK;
        const char* cur = (const char*)Bt[c & 1];

        // issue next-chunk global loads early
        uint4 st0, st1;
        const bool nx = (c + 1 < NCHUNK);
        if (nx) {
            const char* src = zbb + (size_t)(jbase + jc + CHUNK + sjl) * 256 + sir;
            st0 = *(const uint4*)(src);
            st1 = *(const uint4*)(src + 16);
        }

        // fused output zeroing slice (NT streaming; never drained in-loop)
        {
            const int z0 = c * Z4CHK;
            int ze = z0 + Z4CHK; if (ze > zlen) ze = zlen;
            for (int i = z0 + tid; i < ze; i += 512)
                __builtin_nontemporal_store(zero4, zp + i);
        }

        // adaptive threshold for this chunk
        float tau;
        if (c == 0) tau = 0.10f;
        else {
            const float n = 64.f * (float)c;
            const float w = 1.f - 3.f * __frsqrt_rn(2.f * n);
            tau = fmaxf(C_TAU * w * __fsqrt_rn(ss / n), 0.08f);
        }

        // 16 mfma, swapped operands: lane owns output row row_g
        f32x4 acc[4];
#pragma unroll
        for (int t = 0; t < 4; ++t) {
            acc[t] = (f32x4){0.f, 0.f, 0.f, 0.f};
            const char* rp = cur + (size_t)(t * 16 + (lane & 15)) * 256;
#pragma unroll
            for (int ks = 0; ks < 4; ++ks) {
                const short8 bfr = *(const short8*)(rp + ((ks * 64 + (lane >> 4) * 16) ^ swz));
                acc[t] = __builtin_amdgcn_mfma_f32_16x16x32_bf16(bfr, afr[ks], acc[t], 0, 0, 0);
            }
        }

        // sigma accumulation + pass-mask (pure VALU), then ONE atomic per lane
        float ssl = 0.f;
        unsigned int pm = 0u;
        int np = 0;
#pragma unroll
        for (int t = 0; t < 4; ++t) {
#pragma unroll
            for (int r = 0; r < 4; ++r) {
                const int s = t * 4 + r;
                const float val = acc[t][r];
                const int js = jc + t * 16 + ((lane >> 4) << 2) + r;
                const int jg = jbase + js;
                const bool ok = (js < STRIPW) && (jg != row_g);
                ssl += ok ? val * val : 0.f;
                const bool pass = ok && (val > tau);
                pm |= pass ? (1u << s) : 0u;
                np += pass ? 1 : 0;
            }
        }
        int base = 0;
        if (np) base = atomicAdd(&lcnt[rloc], np);
        if (pm) {
#pragma unroll
            for (int t = 0; t < 4; ++t) {
#pragma unroll
                for (int r = 0; r < 4; ++r) {
                    const int s = t * 4 + r;
                    if ((pm >> s) & 1u) {
                        if (base < CAPS) {
                            const float val = acc[t][r];
                            const unsigned int u = __builtin_bit_cast(unsigned int, val);
                            const int jg = jbase + jc + t * 16 + ((lane >> 4) << 2) + r;
                            list[segbase + base] =
                                (((u + 0x8000u) >> 16) << 16) | (unsigned int)jg;
                        }
                        ++base;
                    }
                }
            }
        }
        ssl += __shfl_xor(ssl, 16, 64);   // pool over the row's 4 lanes
        ssl += __shfl_xor(ssl, 32, 64);
        ss += ssl;

        // write staged regs -> other buffer
        if (nx) {
            char* wb = (char*)Bt[(c + 1) & 1] + (size_t)sjl * 256;
            *(uint4*)(wb + sw0) = st0;
            *(uint4*)(wb + sw1) = st1;
        }
        lds_barrier();
    }

    // flush per-(row, strip) counts (this block is the exclusive owner)
    if (tid < 128) {
        const int row = row0 + tid;
        if (row < NROWS) cnt4[row * NSTRIP + strip] = lcnt[tid];
    }
}

// ---------------------------------------------------------------------------
// K3: approx-top-32 of the 16 per-strip segments (packed bf16|idx keys,
// 16 regs/lane = 1024 slots exactly), exact rescore of those 32 with the
// bit-exact sequential f32 FMA chain, exact top-14 by (value desc, idx asc),
// scatter. Rows pre-zeroed by K2. grid = 2500 (4 rows/block, 1 wave/row).
// [R15/R18/R19 byte-identical]
// ---------------------------------------------------------------------------
#define CEK(a, b) { const unsigned int x_ = k[a], y_ = k[b]; \
    k[a] = x_ > y_ ? x_ : y_; k[b] = x_ > y_ ? y_ : x_; }

__global__ __launch_bounds__(256)
void k_select(const float* __restrict__ z32, const int* __restrict__ cnt4,
              const unsigned int* __restrict__ list, float* __restrict__ out) {
    __shared__ float zr[4][HID];
    const int tid = threadIdx.x, wid = tid >> 6, lane = tid & 63;
    const int row = blockIdx.x * 4 + wid;

    *(float2*)&zr[wid][lane * 2] = *(const float2*)(z32 + (size_t)row * HID + lane * 2);
    __syncthreads();

    unsigned int k[16];
#pragma unroll
    for (int t = 0; t < 16; ++t) {
        const int p = t * 64 + lane;          // 0..1023
        const int seg = p >> 6;               // p / CAPS (CAPS = 64)
        const int off = p & 63;
        int cn = cnt4[row * NSTRIP + seg]; if (cn > CAPS) cn = CAPS;
        k[t] = (off < cn) ? list[((size_t)row * NSTRIP + seg) * CAPS + off] : 0u;
    }

    // bitonic sort-16 descending (static indices, sentinel 0)
#pragma unroll
    for (int size = 2; size <= 16; size <<= 1) {
#pragma unroll
        for (int stride = size >> 1; stride > 0; stride >>= 1) {
#pragma unroll
            for (int i = 0; i < 16; ++i) {
                const int j = i ^ stride;
                if (j > i) {
                    if ((i & size) == 0) { CEK(i, j); } else { CEK(j, i); }
                }
            }
        }
    }

    // 32 pops by packed key (keys unique: idx in low bits); lane t keeps pop t
    unsigned int win = 0u;
#pragma unroll 1
    for (int t = 0; t < RESC; ++t) {
        unsigned int m = k[0];
#pragma unroll
        for (int msk = 1; msk <= 32; msk <<= 1) {
            const unsigned int o = (unsigned int)__shfl_xor((int)m, msk, 64);
            m = o > m ? o : m;
        }
        if (lane == t) win = m;
        if (k[0] == m && m != 0u) {
#pragma unroll
            for (int s = 0; s < 15; ++s) k[s] = k[s + 1];
            k[15] = 0u;
        }
    }

    // exact rescore (bit-exact Round-3 chain) of the 32 winners
    float ex = -INFINITY; int idx = 0x7fffffff;
    const bool act = (lane < RESC) && (win != 0u);
    if (act) {
        idx = (int)(win & 0xFFFFu);
        const float* p = z32 + (size_t)idx * HID;
        float a = 0.f;
#pragma unroll
        for (int k4 = 0; k4 < 32; ++k4) {   // strict k-ascending chain
            const float4 bb = *(const float4*)(p + k4 * 4);
            const float4 zz = *(const float4*)&zr[wid][k4 * 4];
            a = fmaf(zz.x, bb.x, a);
            a = fmaf(zz.y, bb.y, a);
            a = fmaf(zz.z, bb.z, a);
            a = fmaf(zz.w, bb.w, a);
        }
        ex = a;
    }

    bool alive = act;
#pragma unroll 1
    for (int t = 0; t < KOUT; ++t) {
        float mv = alive ? ex : -INFINITY;
        int   mi = alive ? idx : 0x7fffffff;
#pragma unroll
        for (int msk = 1; msk <= 32; msk <<= 1) {
            const float ov = __shfl_xor(mv, msk, 64);
            const int   oj = __shfl_xor(mi, msk, 64);
            const bool take = (ov > mv) || (ov == mv && oj < mi);
            mv = take ? ov : mv; mi = take ? oj : mi;
        }
        if (alive && idx == mi) {
            out[(size_t)row * NROWS + mi] = ex;
            alive = false;
        }
    }
}

// ---------------------------------------------------------------------------
extern "C" void kernel_launch(void* const* d_in, const int* in_sizes, int n_in,
                              void* d_out, int out_size, void* d_ws, size_t ws_size,
                              hipStream_t stream) {
    const float* feat = (const float*)d_in[0];
    const float* W    = (const float*)d_in[1];
    const float* b    = (const float*)d_in[2];
    float* out = (float*)d_out;

    char* ws = (char*)d_ws;
    float*          z32  = (float*)ws;                          //  5,120,000 B
    __hip_bfloat16* zb   = (__hip_bfloat16*)(ws + 5120000);     //  2,588,672 B (10112x256)
    int*            cnt4 = (int*)(ws + 7708672);                //    640,000 B (10000x16)
    unsigned int*   lst  = (unsigned int*)(ws + 8348672);       // 40,960,000 B (10000x16x64x4)

    hipLaunchKernelGGL(k_projnorm, dim3(2528),          dim3(128), 0, stream, feat, W, b, z32, zb);
    hipLaunchKernelGGL(k_cand,     dim3(GRIDX, NSTRIP), dim3(512), 0, stream, zb, (f32x4*)out, cnt4, lst);
    hipLaunchKernelGGL(k_select,   dim3(2500),          dim3(256), 0, stream, z32, cnt4, lst, out);
}